// Round 4
// baseline (13.164 us; speedup 1.0000x reference)
//
#include <hip/hip_runtime.h>
#include <hip/hip_bf16.h>

// out[b,k] = relu( sum_d (obs*mask)[b,d]*G[d,k] + s1[b]*W[10,k] + s0[b]*bw[k] )
// G[d,k] = sum_f F[d,f]*W[f,k];  s0[b]=sum_d mask;  s1[b]=sum_d mask*bvec[d]
// B=4096, D=512, K=64.  GEMM in bf16 MFMA (threshold 1.64 >> bf16 err ~0.5).
// 512 blocks x 256 thr (4 waves): wave = k-group of 16, full d=512 per wave
// (16 MFMA steps, G fragments in 64 VGPR) -> no cross-wave combine, 1 barrier.
// 2+ blocks/CU resident => cross-block overlap hides HBM latency.

#define D_DIM 512
#define K_DIM 64
#define B_DIM 4096

typedef __attribute__((ext_vector_type(4))) float f32x4;
typedef __attribute__((ext_vector_type(8))) short bf16x8;

__device__ __forceinline__ unsigned short f2bf(float f) {
    unsigned u = __builtin_bit_cast(unsigned, f);
    u += 0x7fffu + ((u >> 16) & 1u);          // RNE
    return (unsigned short)(u >> 16);
}

// Gf[w][tp][lane][j] (bf16): w=wave/k-group 0..3, tp=k-step 0..15.
// Element = G[d][n], d = tp*32 + (lane>>4)*8 + j, n = w*16 + (lane&15).
__global__ void prep_Gf_kernel(const float* __restrict__ F,
                               const float* __restrict__ W,
                               unsigned short* __restrict__ Gf) {
    int i = blockIdx.x * blockDim.x + threadIdx.x;  // 0..4095
    int lane = i & 63;
    int tp   = (i >> 6) & 15;
    int w    = i >> 10;
    int n     = w * 16 + (lane & 15);
    int dbase = tp * 32 + (lane >> 4) * 8;
    unsigned short v[8];
#pragma unroll
    for (int j = 0; j < 8; ++j) {
        int d = dbase + j;
        float s = 0.f;
#pragma unroll
        for (int f = 0; f < 10; ++f)
            s = fmaf(F[d * 10 + f], W[f * 64 + n], s);
        v[j] = f2bf(s);
    }
    *reinterpret_cast<ushort4*>(Gf + (size_t)i * 8)     = make_ushort4(v[0], v[1], v[2], v[3]);
    *reinterpret_cast<ushort4*>(Gf + (size_t)i * 8 + 4) = make_ushort4(v[4], v[5], v[6], v[7]);
}

__global__ __launch_bounds__(256, 2)
void main_kernel(const float* __restrict__ obs,
                 const float* __restrict__ mask,
                 const float* __restrict__ bvec,
                 const float* __restrict__ W,
                 const float* __restrict__ bw,
                 const unsigned short* __restrict__ Gf,
                 float* __restrict__ out) {
    __shared__ __align__(16) unsigned short Xs[8 * 512];   // 8 KB
    __shared__ float s0s[8], s1s[8];

    const int tid  = threadIdx.x;
    const int lane = tid & 63;
    const int w    = tid >> 6;            // k-group 0..3
    const int rowbase = blockIdx.x * 8;

    // ---- this wave's G fragments: full d=512 x its 16 k's (64 KB total, L2) ----
    bf16x8 gfr[16];
#pragma unroll
    for (int tp = 0; tp < 16; ++tp)
        gfr[tp] = *reinterpret_cast<const bf16x8*>(
            Gf + ((size_t)((w * 16 + tp) * 64 + lane)) * 8);

    const int kk = w * 16 + (lane & 15);
    const float w10 = W[10 * K_DIM + kk];
    const float bwv = bw[kk];

    // ---- stage X=obs*mask -> LDS bf16 (16B-slot XOR swizzle), s0/s1 ----
    {
        const int r = tid >> 5;      // row 0..7 (32 threads per row)
        const int c = tid & 31;
        const float* orow = obs  + (size_t)(rowbase + r) * D_DIM;
        const float* mrow = mask + (size_t)(rowbase + r) * D_DIM;
        f32x4 o[4], m[4], bv[4];
#pragma unroll
        for (int j = 0; j < 4; ++j) {
            int d = c * 4 + 128 * j;
            o[j]  = *reinterpret_cast<const f32x4*>(orow + d);
            m[j]  = *reinterpret_cast<const f32x4*>(mrow + d);
            bv[j] = *reinterpret_cast<const f32x4*>(bvec + d);
        }
        float p0 = 0.f, p1 = 0.f;
        const int swz = r << 4;
        char* xb = reinterpret_cast<char*>(Xs);
#pragma unroll
        for (int j = 0; j < 4; ++j) {
            ushort4 pk;
            pk.x = f2bf(o[j].x * m[j].x);
            pk.y = f2bf(o[j].y * m[j].y);
            pk.z = f2bf(o[j].z * m[j].z);
            pk.w = f2bf(o[j].w * m[j].w);
            int byteoff = r * 1024 + ((c * 8 + 256 * j) ^ swz);
            *reinterpret_cast<ushort4*>(xb + byteoff) = pk;
            p0 += (m[j].x + m[j].y) + (m[j].z + m[j].w);
            p1 = fmaf(m[j].x, bv[j].x, p1);
            p1 = fmaf(m[j].y, bv[j].y, p1);
            p1 = fmaf(m[j].z, bv[j].z, p1);
            p1 = fmaf(m[j].w, bv[j].w, p1);
        }
#pragma unroll
        for (int s = 1; s <= 16; s <<= 1) {   // reduce across the 32-lane row-group
            p0 += __shfl_xor(p0, s, 64);
            p1 += __shfl_xor(p1, s, 64);
        }
        if (c == 0) { s0s[r] = p0; s1s[r] = p1; }
    }
    __syncthreads();

    // ---- MFMA: 16 steps of K=32, full d; A rows 8..15 duplicate 0..7 ----
    f32x4 acc = {0.f, 0.f, 0.f, 0.f};
    {
        const int arow = lane & 7;
        const int g    = lane >> 4;
        const char* xb = reinterpret_cast<const char*>(Xs);
#pragma unroll
        for (int tp = 0; tp < 16; ++tp) {
            int byteoff = arow * 1024 + ((64 * tp + 16 * g) ^ (arow << 4));
            bf16x8 a = *reinterpret_cast<const bf16x8*>(xb + byteoff);
            acc = __builtin_amdgcn_mfma_f32_16x16x32_bf16(a, gfr[tp], acc, 0, 0, 0);
        }
    }

    // ---- epilogue: rows 0..7 live in lanes 0..31 ----
    if (lane < 32) {
        const int g = lane >> 4;     // 0 or 1
#pragma unroll
        for (int r = 0; r < 4; ++r) {
            const int rowl = g * 4 + r;          // C/D: row=(lane>>4)*4+reg
            float tot = acc[r];
            tot = fmaf(s1s[rowl], w10, tot);
            tot = fmaf(s0s[rowl], bwv, tot);
            out[(size_t)(rowbase + rowl) * K_DIM + kk] = fmaxf(tot, 0.f);
        }
    }
}

extern "C" void kernel_launch(void* const* d_in, const int* in_sizes, int n_in,
                              void* d_out, int out_size, void* d_ws, size_t ws_size,
                              hipStream_t stream) {
    const float* obs  = (const float*)d_in[0];  // [4096, 512]
    const float* mask = (const float*)d_in[1];  // [4096, 512]
    const float* F    = (const float*)d_in[2];  // [1, 512, 10]
    const float* bvec = (const float*)d_in[3];  // [1, 512, 1]
    const float* W    = (const float*)d_in[4];  // [11, 64]
    const float* bw   = (const float*)d_in[5];  // [64]
    float* out = (float*)d_out;                 // [4096, 64]
    unsigned short* Gf = (unsigned short*)d_ws; // 32768 bf16 = 64 KB

    prep_Gf_kernel<<<16, 256, 0, stream>>>(F, W, Gf);
    main_kernel<<<B_DIM / 8, 256, 0, stream>>>(obs, mask, bvec, W, bw, Gf, out);
}